// Round 2
// baseline (269.090 us; speedup 1.0000x reference)
//
#include <hip/hip_runtime.h>
#include <stdint.h>

typedef unsigned short u16;
typedef __bf16 bf16x8 __attribute__((ext_vector_type(8)));
typedef float f32x4 __attribute__((ext_vector_type(4)));
typedef unsigned short u16x8 __attribute__((ext_vector_type(8)));

#define TTOK 2048
#define DIMSZ 1024
#define NROUT 16
#define INTERSZ 512

__device__ __forceinline__ u16 f2bf(float f) {
    unsigned int u = __builtin_bit_cast(unsigned int, f);
    unsigned int r = u + 0x7FFFu + ((u >> 16) & 1u);
    return (u16)(r >> 16);
}

__device__ __forceinline__ u16x8 cvt8(float4 a, float4 b) {
    u16x8 o;
    o[0] = f2bf(a.x); o[1] = f2bf(a.y); o[2] = f2bf(a.z); o[3] = f2bf(a.w);
    o[4] = f2bf(b.x); o[5] = f2bf(b.y); o[6] = f2bf(b.z); o[7] = f2bf(b.w);
    return o;
}

__device__ __forceinline__ void gl2lds16(const void* g, void* l) {
    __builtin_amdgcn_global_load_lds(
        (const __attribute__((address_space(1))) void*)(uintptr_t)g,
        (__attribute__((address_space(3))) void*)(uintptr_t)l,
        16, 0, 0);
}

// ---- prep: gate + Xbf cast + zero(out). One block per token. ----
// Weight casts are gone: GEMMs consume fp32 weights directly (cvt during LDS staging).
__global__ __launch_bounds__(256) void prep(
    const float* __restrict__ x, const float* __restrict__ gw,
    int* __restrict__ topi, float2* __restrict__ topw,
    u16* __restrict__ Xbf, float* __restrict__ out) {
    const int tid = threadIdx.x;
    const int t = blockIdx.x;
    const int wave = tid >> 6, lane = tid & 63;
    const int d0 = tid * 4;
    // zero the output row (race-free accumulate target for gemm2u)
    *(float4*)(out + (size_t)t * DIMSZ + d0) = make_float4(0.f, 0.f, 0.f, 0.f);
    float4 xv = *(const float4*)(x + (size_t)t * DIMSZ + d0);
    ushort4 o;
    o.x = f2bf(xv.x); o.y = f2bf(xv.y); o.z = f2bf(xv.z); o.w = f2bf(xv.w);
    *(ushort4*)&Xbf[(size_t)t * DIMSZ + d0] = o;

    float acc[16];
    #pragma unroll
    for (int e = 0; e < 16; ++e) {
        float4 g = *(const float4*)(gw + e * DIMSZ + d0);
        acc[e] = xv.x * g.x + xv.y * g.y + xv.z * g.z + xv.w * g.w;
    }
    #pragma unroll
    for (int off = 32; off > 0; off >>= 1) {
        #pragma unroll
        for (int e = 0; e < 16; ++e) acc[e] += __shfl_xor(acc[e], off);
    }
    __shared__ float part[4][16];
    __shared__ float sfin[16];
    if (lane < 16) part[wave][lane] = acc[lane];
    __syncthreads();
    if (wave == 0 && lane < 16) {
        float s = part[0][lane] + part[1][lane] + part[2][lane] + part[3][lane];
        sfin[lane] = 1.f / (1.f + expf(-s));
    }
    __syncthreads();
    if (tid == 0) {
        int i0 = 0; float v0 = sfin[0];
        #pragma unroll
        for (int e = 1; e < 16; ++e) { float v = sfin[e]; if (v > v0) { v0 = v; i0 = e; } }
        int i1 = -1; float v1 = -1e30f;
        #pragma unroll
        for (int e = 0; e < 16; ++e) { float v = sfin[e]; if (e != i0 && v > v1) { v1 = v; i1 = e; } }
        float inv = 1.f / (v0 + v1);
        topi[t] = i0 | (i1 << 8);
        topw[t] = make_float2(v0 * inv, v1 * inv);
    }
}

// ---- route: one block per expert; block-wide prefix sum -> ordered compact lists ----
__global__ __launch_bounds__(256) void route_kernel(
    const int* __restrict__ topi, const float2* __restrict__ topw,
    int* __restrict__ counts, int* __restrict__ tokidx, float* __restrict__ tokw) {
    const int e = blockIdx.x;
    const int tid = threadIdx.x;
    int p[8]; int m[8]; int cnt = 0;
    #pragma unroll
    for (int j = 0; j < 8; ++j) {
        int t = tid * 8 + j;
        p[j] = topi[t];
        m[j] = ((p[j] & 255) == e) || ((p[j] >> 8) == e) ? 1 : 0;
        cnt += m[j];
    }
    const int lane = tid & 63, wave = tid >> 6;
    int v = cnt;
    #pragma unroll
    for (int off = 1; off < 64; off <<= 1) {
        int u = __shfl_up(v, off);
        if (lane >= off) v += u;
    }
    __shared__ int wsum[4];
    if (lane == 63) wsum[wave] = v;
    __syncthreads();
    int wbase = 0;
    #pragma unroll
    for (int w = 0; w < 4; ++w) wbase += (w < wave) ? wsum[w] : 0;
    int base = wbase + v - cnt;
    #pragma unroll
    for (int j = 0; j < 8; ++j) {
        if (m[j]) {
            int t = tid * 8 + j;
            float2 w2 = topw[t];
            tokidx[e * TTOK + base] = t;
            tokw[e * TTOK + base] = ((p[j] & 255) == e) ? w2.x : w2.y;
            ++base;
        }
    }
    if (tid == 0) counts[e] = wsum[0] + wsum[1] + wsum[2] + wsum[3];
}

// ---- GEMM1 sparse: BM=64 BN=128 BK=64, 4 waves (2x2), wave tile 32x64 ----
// z < NROUT routed, z in {16,17} shared halves.
// B operands (w1/w3/sw1/sw3) are fp32: register-prefetched across K-tiles (T14),
// converted to bf16 during the LDS write. A (Xbf) stays global_load_lds direct.
__global__ __launch_bounds__(256) void gemm1s(
    const u16* __restrict__ Xbf,
    const float* __restrict__ w1f, const float* __restrict__ w3f,
    const float* __restrict__ sw1f, const float* __restrict__ sw3f,
    const int* __restrict__ counts,
    const int* __restrict__ tokidx, const float* __restrict__ tokw,
    u16* __restrict__ Hc, u16* __restrict__ Hs) {
    const int e = blockIdx.z;
    const int tid = threadIdx.x;
    const int cnt = (e < NROUT) ? counts[e] : TTOK;
    const int m0 = blockIdx.y * 64;
    if (m0 >= cnt) return;
    const int n0 = blockIdx.x * 128;
    __shared__ u16 As[64 * 64], B1s[128 * 64], B3s[128 * 64];
    const float* B1f = (e < NROUT ? w1f + (size_t)e * INTERSZ * DIMSZ
                                  : sw1f + (size_t)(e - NROUT) * INTERSZ * DIMSZ)
                       + (size_t)n0 * DIMSZ;
    const float* B3f = (e < NROUT ? w3f + (size_t)e * INTERSZ * DIMSZ
                                  : sw3f + (size_t)(e - NROUT) * INTERSZ * DIMSZ)
                       + (size_t)n0 * DIMSZ;

    int rowa[2], cgsa[2]; size_t arow[2];
    #pragma unroll
    for (int i = 0; i < 2; ++i) {
        int c = tid + i * 256;
        rowa[i] = c >> 3;
        cgsa[i] = ((c & 7) ^ (rowa[i] & 7)) * 8;
        int slot = m0 + rowa[i];
        int g;
        if (e < NROUT) g = (slot < cnt) ? tokidx[e * TTOK + slot] : 0;
        else           g = slot;
        arow[i] = (size_t)g * DIMSZ;
    }
    int rowb[4], cgsb[4];
    #pragma unroll
    for (int i = 0; i < 4; ++i) {
        int c = tid + i * 256;
        rowb[i] = c >> 3;
        cgsb[i] = ((c & 7) ^ (rowb[i] & 7)) * 8;
    }
    f32x4 acc1[2][4] = {}; f32x4 acc3[2][4] = {};
    const int wave = tid >> 6, lane = tid & 63;
    const int wm = (wave >> 1) * 32, wn = (wave & 1) * 64;
    const int lr = lane & 15, lq = lane >> 4;
    const int NKT = DIMSZ / 64;

    // prologue: prefetch B tile kt=0 into registers
    float4 pb1[4][2], pb3[4][2];
    #pragma unroll
    for (int i = 0; i < 4; ++i) {
        const float* p1 = B1f + (size_t)rowb[i] * DIMSZ + cgsb[i];
        const float* p3 = B3f + (size_t)rowb[i] * DIMSZ + cgsb[i];
        pb1[i][0] = *(const float4*)p1; pb1[i][1] = *(const float4*)(p1 + 4);
        pb3[i][0] = *(const float4*)p3; pb3[i][1] = *(const float4*)(p3 + 4);
    }

    for (int kt = 0; kt < NKT; ++kt) {
        const int k0 = kt * 64;
        #pragma unroll
        for (int i = 0; i < 2; ++i) {
            int c = tid + i * 256;
            gl2lds16(Xbf + arow[i] + k0 + cgsa[i], &As[c * 8]);
        }
        // convert staged fp32 regs -> bf16 LDS (same swizzled layout as before)
        #pragma unroll
        for (int i = 0; i < 4; ++i) {
            int c = tid + i * 256;
            *(u16x8*)&B1s[c * 8] = cvt8(pb1[i][0], pb1[i][1]);
            *(u16x8*)&B3s[c * 8] = cvt8(pb3[i][0], pb3[i][1]);
        }
        __syncthreads();
        // prefetch next B tile; in flight during the MFMA phase below
        if (kt + 1 < NKT) {
            const int kn = k0 + 64;
            #pragma unroll
            for (int i = 0; i < 4; ++i) {
                const float* p1 = B1f + (size_t)rowb[i] * DIMSZ + kn + cgsb[i];
                const float* p3 = B3f + (size_t)rowb[i] * DIMSZ + kn + cgsb[i];
                pb1[i][0] = *(const float4*)p1; pb1[i][1] = *(const float4*)(p1 + 4);
                pb3[i][0] = *(const float4*)p3; pb3[i][1] = *(const float4*)(p3 + 4);
            }
        }
        #pragma unroll
        for (int ks = 0; ks < 2; ++ks) {
            bf16x8 af[2], b1f[4], b3f[4];
            const int g = lq + ks * 4;
            #pragma unroll
            for (int mt = 0; mt < 2; ++mt) {
                int m = wm + mt * 16 + lr;
                af[mt] = *(const bf16x8*)&As[(m * 8 + (g ^ (m & 7))) * 8];
            }
            #pragma unroll
            for (int nt = 0; nt < 4; ++nt) {
                int n = wn + nt * 16 + lr;
                int ch = (n * 8 + (g ^ (n & 7))) * 8;
                b1f[nt] = *(const bf16x8*)&B1s[ch];
                b3f[nt] = *(const bf16x8*)&B3s[ch];
            }
            #pragma unroll
            for (int mt = 0; mt < 2; ++mt) {
                #pragma unroll
                for (int nt = 0; nt < 4; ++nt) {
                    acc1[mt][nt] = __builtin_amdgcn_mfma_f32_16x16x32_bf16(af[mt], b1f[nt], acc1[mt][nt], 0, 0, 0);
                    acc3[mt][nt] = __builtin_amdgcn_mfma_f32_16x16x32_bf16(af[mt], b3f[nt], acc3[mt][nt], 0, 0, 0);
                }
            }
        }
        __syncthreads();
    }
    #pragma unroll
    for (int mt = 0; mt < 2; ++mt) {
        #pragma unroll
        for (int nt = 0; nt < 4; ++nt) {
            #pragma unroll
            for (int r = 0; r < 4; ++r) {
                int m = wm + mt * 16 + lq * 4 + r;
                int n = wn + nt * 16 + lr;
                int slot = m0 + m;
                bool valid = slot < cnt;
                float h1 = acc1[mt][nt][r], h3 = acc3[mt][nt][r];
                float hv = 0.f;
                if (valid) {
                    float tw = (e < NROUT) ? tokw[e * TTOK + slot] : 1.0f;
                    hv = h1 / (1.f + __expf(-h1)) * h3 * tw;
                }
                if (e < NROUT)
                    Hc[((size_t)e * TTOK + slot) * INTERSZ + n0 + n] = f2bf(hv);
                else
                    Hs[(size_t)slot * DIMSZ + (e - NROUT) * INTERSZ + n0 + n] = f2bf(hv);
            }
        }
    }
}

// ---- GEMM2 unified: BM=64 BN=128; out zero-initialized, ALL blocks atomicAdd ----
// z<16 routed (K=512, gathered token scatter), z==16 shared (K=1024, identity rows)
// B operands (w2/sw2) fp32, register-prefetched + cvt during LDS staging.
__global__ __launch_bounds__(256) void gemm2u(
    const u16* __restrict__ Hc, const u16* __restrict__ Hs,
    const float* __restrict__ w2f, const float* __restrict__ sw2f,
    const int* __restrict__ counts, const int* __restrict__ tokidx,
    float* __restrict__ out) {
    const int e = blockIdx.z;
    const bool routed = (e < NROUT);
    const int cnt = routed ? counts[e] : TTOK;
    const int m0 = blockIdx.y * 64;
    if (m0 >= cnt) return;
    const int n0 = blockIdx.x * 128;
    const int klen = routed ? INTERSZ : DIMSZ;
    __shared__ u16 As[64 * 64], Bs[128 * 64];
    const u16* A0 = routed ? Hc + ((size_t)e * TTOK + m0) * INTERSZ
                           : Hs + (size_t)m0 * DIMSZ;
    const float* B0f = routed ? w2f + (size_t)e * DIMSZ * INTERSZ + (size_t)n0 * INTERSZ
                              : sw2f + (size_t)n0 * DIMSZ;
    const int tid = threadIdx.x;
    const int wave = tid >> 6, lane = tid & 63;
    const int wm = (wave >> 1) * 32, wn = (wave & 1) * 64;
    const int lr = lane & 15, lq = lane >> 4;

    int rowa[2], cgsa[2];
    #pragma unroll
    for (int i = 0; i < 2; ++i) {
        int c = tid + i * 256;
        rowa[i] = c >> 3;
        cgsa[i] = ((c & 7) ^ (rowa[i] & 7)) * 8;
    }
    int rowb[4], cgsb[4];
    #pragma unroll
    for (int i = 0; i < 4; ++i) {
        int c = tid + i * 256;
        rowb[i] = c >> 3;
        cgsb[i] = ((c & 7) ^ (rowb[i] & 7)) * 8;
    }

    const int NKT = klen / 64;
    float4 pb[4][2];
    #pragma unroll
    for (int i = 0; i < 4; ++i) {
        const float* p = B0f + (size_t)rowb[i] * klen + cgsb[i];
        pb[i][0] = *(const float4*)p; pb[i][1] = *(const float4*)(p + 4);
    }

    f32x4 acc[2][4] = {};
    for (int kt = 0; kt < NKT; ++kt) {
        const int k0 = kt * 64;
        #pragma unroll
        for (int i = 0; i < 2; ++i) {
            int c = tid + i * 256;
            gl2lds16(A0 + (size_t)rowa[i] * klen + k0 + cgsa[i], &As[c * 8]);
        }
        #pragma unroll
        for (int i = 0; i < 4; ++i) {
            int c = tid + i * 256;
            *(u16x8*)&Bs[c * 8] = cvt8(pb[i][0], pb[i][1]);
        }
        __syncthreads();
        if (kt + 1 < NKT) {
            const int kn = k0 + 64;
            #pragma unroll
            for (int i = 0; i < 4; ++i) {
                const float* p = B0f + (size_t)rowb[i] * klen + kn + cgsb[i];
                pb[i][0] = *(const float4*)p; pb[i][1] = *(const float4*)(p + 4);
            }
        }
        #pragma unroll
        for (int ks = 0; ks < 2; ++ks) {
            bf16x8 af[2], bfr[4];
            const int g = lq + ks * 4;
            #pragma unroll
            for (int mt = 0; mt < 2; ++mt) {
                int m = wm + mt * 16 + lr;
                af[mt] = *(const bf16x8*)&As[(m * 8 + (g ^ (m & 7))) * 8];
            }
            #pragma unroll
            for (int nt = 0; nt < 4; ++nt) {
                int n = wn + nt * 16 + lr;
                bfr[nt] = *(const bf16x8*)&Bs[(n * 8 + (g ^ (n & 7))) * 8];
            }
            #pragma unroll
            for (int mt = 0; mt < 2; ++mt) {
                #pragma unroll
                for (int nt = 0; nt < 4; ++nt) {
                    acc[mt][nt] = __builtin_amdgcn_mfma_f32_16x16x32_bf16(af[mt], bfr[nt], acc[mt][nt], 0, 0, 0);
                }
            }
        }
        __syncthreads();
    }
    #pragma unroll
    for (int mt = 0; mt < 2; ++mt) {
        #pragma unroll
        for (int r = 0; r < 4; ++r) {
            int m = wm + mt * 16 + lq * 4 + r;
            int slot = m0 + m;
            if (slot < cnt) {
                int t = routed ? tokidx[e * TTOK + slot] : slot;
                #pragma unroll
                for (int nt = 0; nt < 4; ++nt) {
                    int n = wn + nt * 16 + lr;
                    unsafeAtomicAdd(&out[(size_t)t * DIMSZ + n0 + n], acc[mt][nt][r]);
                }
            }
        }
    }
}

extern "C" void kernel_launch(void* const* d_in, const int* in_sizes, int n_in,
                              void* d_out, int out_size, void* d_ws, size_t ws_size,
                              hipStream_t stream) {
    const float* x      = (const float*)d_in[0];
    const float* gate_w = (const float*)d_in[1];
    const float* w1     = (const float*)d_in[2];
    const float* w2     = (const float*)d_in[3];
    const float* w3     = (const float*)d_in[4];
    const float* sw1    = (const float*)d_in[5];
    const float* sw2    = (const float*)d_in[6];
    const float* sw3    = (const float*)d_in[7];
    float* out = (float*)d_out;

    char* ws = (char*)d_ws;
    const size_t SZ_XBF = (size_t)TTOK * DIMSZ * 2;
    u16*   Xbf    = (u16*)ws;
    char*  route  = ws + SZ_XBF;
    int*   counts = (int*)route;
    int*   topi   = (int*)(route + 256);
    float2* topw  = (float2*)(route + 256 + TTOK * 4);
    int*   tokidx = (int*)(route + 256 + TTOK * 12);
    float* tokw   = (float*)(route + 256 + TTOK * 12 + 16 * TTOK * 4);
    char*  hbuf   = route + 256 + TTOK * 12 + 2 * (size_t)16 * TTOK * 4;
    u16*   Hc     = (u16*)hbuf;                                        // [16][2048][512]
    u16*   Hs     = (u16*)(hbuf + (size_t)NROUT * TTOK * INTERSZ * 2); // [2048][1024]

    prep<<<dim3(2048), 256, 0, stream>>>(x, gate_w, topi, topw, Xbf, out);
    route_kernel<<<NROUT, 256, 0, stream>>>(topi, topw, counts, tokidx, tokw);
    gemm1s<<<dim3(INTERSZ / 128, TTOK / 64, NROUT + 2), 256, 0, stream>>>(
        Xbf, w1, w3, sw1, sw3, counts, tokidx, tokw, Hc, Hs);
    gemm2u<<<dim3(DIMSZ / 128, TTOK / 64, NROUT + 1), 256, 0, stream>>>(
        Hc, Hs, w2, sw2, counts, tokidx, out);
}

// Round 3
// 234.260 us; speedup vs baseline: 1.1487x; 1.1487x over previous
//
#include <hip/hip_runtime.h>
#include <stdint.h>

typedef unsigned short u16;
typedef __bf16 bf16x8 __attribute__((ext_vector_type(8)));
typedef float f32x4 __attribute__((ext_vector_type(4)));
typedef unsigned short u16x8 __attribute__((ext_vector_type(8)));

#define TTOK 2048
#define DIMSZ 1024
#define NROUT 16
#define INTERSZ 512
#define BK 128
#define CHK 16   // BK/8 chunks of 8 u16 per row

__device__ __forceinline__ u16 f2bf(float f) {
    unsigned int u = __builtin_bit_cast(unsigned int, f);
    unsigned int r = u + 0x7FFFu + ((u >> 16) & 1u);
    return (u16)(r >> 16);
}

__device__ __forceinline__ void gl2lds16(const void* g, void* l) {
    __builtin_amdgcn_global_load_lds(
        (const __attribute__((address_space(1))) void*)(uintptr_t)g,
        (__attribute__((address_space(3))) void*)(uintptr_t)l,
        16, 0, 0);
}

// ---- prep: grid.y<3 = weight cast groups (ILP-unrolled); grid.y==3 = gate+Xbf+zero ----
#define NA4 (NROUT * INTERSZ * DIMSZ / 4)
#define NB4 (DIMSZ * DIMSZ / 4)
#define NA8 (NA4 / 2)
#define NR8 ((NA4 + NB4) / 2)
#define CAST_BLKS 1152   // NR8 / (256 * 4)
__global__ __launch_bounds__(256) void prep(
    const float* __restrict__ w1, const float* __restrict__ sw1,
    const float* __restrict__ w3, const float* __restrict__ sw3,
    const float* __restrict__ w2, const float* __restrict__ sw2,
    u16* __restrict__ W1b, u16* __restrict__ W3b, u16* __restrict__ W2b,
    const float* __restrict__ x, const float* __restrict__ gw,
    int* __restrict__ topi, float2* __restrict__ topw,
    u16* __restrict__ Xbf, float* __restrict__ out) {
    const int r = blockIdx.y;
    const int tid = threadIdx.x;
    if (r < 3) {
        if (blockIdx.x >= CAST_BLKS) return;
        const float* a; const float* b; u16* d;
        if (r == 0)      { a = w1; b = sw1; d = W1b; }
        else if (r == 1) { a = w3; b = sw3; d = W3b; }
        else             { a = w2; b = sw2; d = W2b; }
        // 4 independent j per thread: 8 float4 loads in flight before converts.
        float4 v[8];
        size_t js[4];
        #pragma unroll
        for (int k = 0; k < 4; ++k) {
            size_t j = (size_t)blockIdx.x * 1024 + k * 256 + tid;
            js[k] = j;
            const float4* src = (j < NA8) ? (const float4*)a + 2 * j
                                          : (const float4*)b + 2 * (j - NA8);
            v[2 * k]     = src[0];
            v[2 * k + 1] = src[1];
        }
        #pragma unroll
        for (int k = 0; k < 4; ++k) {
            u16x8 o;
            o[0] = f2bf(v[2 * k].x);     o[1] = f2bf(v[2 * k].y);
            o[2] = f2bf(v[2 * k].z);     o[3] = f2bf(v[2 * k].w);
            o[4] = f2bf(v[2 * k + 1].x); o[5] = f2bf(v[2 * k + 1].y);
            o[6] = f2bf(v[2 * k + 1].z); o[7] = f2bf(v[2 * k + 1].w);
            *(u16x8*)&d[js[k] * 8] = o;
        }
        return;
    }
    // gate branch: one block per token
    const int t = blockIdx.x;
    const int wave = tid >> 6, lane = tid & 63;
    const int d0 = tid * 4;
    *(float4*)(out + (size_t)t * DIMSZ + d0) = make_float4(0.f, 0.f, 0.f, 0.f);
    float4 xv = *(const float4*)(x + (size_t)t * DIMSZ + d0);
    ushort4 o;
    o.x = f2bf(xv.x); o.y = f2bf(xv.y); o.z = f2bf(xv.z); o.w = f2bf(xv.w);
    *(ushort4*)&Xbf[(size_t)t * DIMSZ + d0] = o;

    float acc[16];
    #pragma unroll
    for (int e = 0; e < 16; ++e) {
        float4 g = *(const float4*)(gw + e * DIMSZ + d0);
        acc[e] = xv.x * g.x + xv.y * g.y + xv.z * g.z + xv.w * g.w;
    }
    #pragma unroll
    for (int off = 32; off > 0; off >>= 1) {
        #pragma unroll
        for (int e = 0; e < 16; ++e) acc[e] += __shfl_xor(acc[e], off);
    }
    __shared__ float part[4][16];
    __shared__ float sfin[16];
    if (lane < 16) part[wave][lane] = acc[lane];
    __syncthreads();
    if (wave == 0 && lane < 16) {
        float s = part[0][lane] + part[1][lane] + part[2][lane] + part[3][lane];
        sfin[lane] = 1.f / (1.f + expf(-s));
    }
    __syncthreads();
    if (tid == 0) {
        int i0 = 0; float v0 = sfin[0];
        #pragma unroll
        for (int e = 1; e < 16; ++e) { float v = sfin[e]; if (v > v0) { v0 = v; i0 = e; } }
        int i1 = -1; float v1 = -1e30f;
        #pragma unroll
        for (int e = 0; e < 16; ++e) { float v = sfin[e]; if (e != i0 && v > v1) { v1 = v; i1 = e; } }
        float inv = 1.f / (v0 + v1);
        topi[t] = i0 | (i1 << 8);
        topw[t] = make_float2(v0 * inv, v1 * inv);
    }
}

// ---- route: one block per expert; block-wide prefix sum -> ordered compact lists ----
__global__ __launch_bounds__(256) void route_kernel(
    const int* __restrict__ topi, const float2* __restrict__ topw,
    int* __restrict__ counts, int* __restrict__ tokidx, float* __restrict__ tokw) {
    const int e = blockIdx.x;
    const int tid = threadIdx.x;
    int p[8]; int m[8]; int cnt = 0;
    #pragma unroll
    for (int j = 0; j < 8; ++j) {
        int t = tid * 8 + j;
        p[j] = topi[t];
        m[j] = ((p[j] & 255) == e) || ((p[j] >> 8) == e) ? 1 : 0;
        cnt += m[j];
    }
    const int lane = tid & 63, wave = tid >> 6;
    int v = cnt;
    #pragma unroll
    for (int off = 1; off < 64; off <<= 1) {
        int u = __shfl_up(v, off);
        if (lane >= off) v += u;
    }
    __shared__ int wsum[4];
    if (lane == 63) wsum[wave] = v;
    __syncthreads();
    int wbase = 0;
    #pragma unroll
    for (int w = 0; w < 4; ++w) wbase += (w < wave) ? wsum[w] : 0;
    int base = wbase + v - cnt;
    #pragma unroll
    for (int j = 0; j < 8; ++j) {
        if (m[j]) {
            int t = tid * 8 + j;
            float2 w2 = topw[t];
            tokidx[e * TTOK + base] = t;
            tokw[e * TTOK + base] = ((p[j] & 255) == e) ? w2.x : w2.y;
            ++base;
        }
    }
    if (tid == 0) counts[e] = wsum[0] + wsum[1] + wsum[2] + wsum[3];
}

// ---- GEMM1 sparse: BM=64 BN=64 BK=128, 4 waves (2x2), wave tile 32x32 ----
// z < NROUT routed, z in {16,17} shared halves. bf16 weights via global_load_lds.
__global__ __launch_bounds__(256) void gemm1s(
    const u16* __restrict__ Xbf, const u16* __restrict__ W1b,
    const u16* __restrict__ W3b, const int* __restrict__ counts,
    const int* __restrict__ tokidx, const float* __restrict__ tokw,
    u16* __restrict__ Hc, u16* __restrict__ Hs) {
    const int e = blockIdx.z;
    const int cnt = (e < NROUT) ? counts[e] : TTOK;
    const int m0 = blockIdx.y * 64;
    if (m0 >= cnt) return;
    const int n0 = blockIdx.x * 64;
    __shared__ u16 As[64 * BK], B1s[64 * BK], B3s[64 * BK];
    // shared halves (e=16,17) are appended rows of W1b/W3b: base row = e*INTERSZ + n0
    const u16* B1 = W1b + ((size_t)e * INTERSZ + n0) * DIMSZ;
    const u16* B3 = W3b + ((size_t)e * INTERSZ + n0) * DIMSZ;
    const int tid = threadIdx.x;

    int row[4], cgs[4]; size_t arow[4];
    #pragma unroll
    for (int i = 0; i < 4; ++i) {
        int c = tid + i * 256;
        row[i] = c >> 4;
        cgs[i] = ((c & 15) ^ (row[i] & 7)) * 8;
        int slot = m0 + row[i];
        int g;
        if (e < NROUT) g = (slot < cnt) ? tokidx[e * TTOK + slot] : 0;
        else           g = slot;
        arow[i] = (size_t)g * DIMSZ;
    }
    f32x4 acc1[2][2] = {}; f32x4 acc3[2][2] = {};
    const int wave = tid >> 6, lane = tid & 63;
    const int wm = (wave >> 1) * 32, wn = (wave & 1) * 32;
    const int lr = lane & 15, lq = lane >> 4;

    for (int kt = 0; kt < DIMSZ / BK; ++kt) {
        const int k0 = kt * BK;
        #pragma unroll
        for (int i = 0; i < 4; ++i) {
            int c = tid + i * 256;
            gl2lds16(Xbf + arow[i] + k0 + cgs[i], &As[c * 8]);
            size_t boff = (size_t)row[i] * DIMSZ + k0 + cgs[i];
            gl2lds16(B1 + boff, &B1s[c * 8]);
            gl2lds16(B3 + boff, &B3s[c * 8]);
        }
        __syncthreads();
        #pragma unroll
        for (int ks = 0; ks < 4; ++ks) {
            bf16x8 af[2], b1f[2], b3f[2];
            const int g = ks * 4 + lq;
            #pragma unroll
            for (int mt = 0; mt < 2; ++mt) {
                int m = wm + mt * 16 + lr;
                af[mt] = *(const bf16x8*)&As[(m * CHK + (g ^ (m & 7))) * 8];
            }
            #pragma unroll
            for (int nt = 0; nt < 2; ++nt) {
                int n = wn + nt * 16 + lr;
                int ch = (n * CHK + (g ^ (n & 7))) * 8;
                b1f[nt] = *(const bf16x8*)&B1s[ch];
                b3f[nt] = *(const bf16x8*)&B3s[ch];
            }
            #pragma unroll
            for (int mt = 0; mt < 2; ++mt) {
                #pragma unroll
                for (int nt = 0; nt < 2; ++nt) {
                    acc1[mt][nt] = __builtin_amdgcn_mfma_f32_16x16x32_bf16(af[mt], b1f[nt], acc1[mt][nt], 0, 0, 0);
                    acc3[mt][nt] = __builtin_amdgcn_mfma_f32_16x16x32_bf16(af[mt], b3f[nt], acc3[mt][nt], 0, 0, 0);
                }
            }
        }
        __syncthreads();
    }
    #pragma unroll
    for (int mt = 0; mt < 2; ++mt) {
        #pragma unroll
        for (int nt = 0; nt < 2; ++nt) {
            #pragma unroll
            for (int r = 0; r < 4; ++r) {
                int m = wm + mt * 16 + lq * 4 + r;
                int n = wn + nt * 16 + lr;
                int slot = m0 + m;
                bool valid = slot < cnt;
                float h1 = acc1[mt][nt][r], h3 = acc3[mt][nt][r];
                float hv = 0.f;
                if (valid) {
                    float tw = (e < NROUT) ? tokw[e * TTOK + slot] : 1.0f;
                    hv = h1 / (1.f + __expf(-h1)) * h3 * tw;
                }
                if (e < NROUT)
                    Hc[((size_t)e * TTOK + slot) * INTERSZ + n0 + n] = f2bf(hv);
                else
                    Hs[(size_t)slot * DIMSZ + (e - NROUT) * INTERSZ + n0 + n] = f2bf(hv);
            }
        }
    }
}

// ---- GEMM2 unified: BM=64 BN=64 BK=128; out zero-initialized, atomicAdd ----
// z<16 routed (K=512), z==16 shared (K=1024, identity rows)
__global__ __launch_bounds__(256) void gemm2u(
    const u16* __restrict__ Hc, const u16* __restrict__ Hs,
    const u16* __restrict__ W2b, const u16* __restrict__ W2sb,
    const int* __restrict__ counts, const int* __restrict__ tokidx,
    float* __restrict__ out) {
    const int e = blockIdx.z;
    const bool routed = (e < NROUT);
    const int cnt = routed ? counts[e] : TTOK;
    const int m0 = blockIdx.y * 64;
    if (m0 >= cnt) return;
    const int n0 = blockIdx.x * 64;
    const int klen = routed ? INTERSZ : DIMSZ;
    __shared__ u16 As[64 * BK], Bs[64 * BK];
    const u16* A0 = routed ? Hc + ((size_t)e * TTOK + m0) * INTERSZ
                           : Hs + (size_t)m0 * DIMSZ;
    const u16* B0 = routed ? W2b + ((size_t)e * DIMSZ + n0) * INTERSZ
                           : W2sb + (size_t)n0 * DIMSZ;
    const int tid = threadIdx.x;
    const int wave = tid >> 6, lane = tid & 63;
    const int wm = (wave >> 1) * 32, wn = (wave & 1) * 32;
    const int lr = lane & 15, lq = lane >> 4;

    int row[4], cgs[4];
    #pragma unroll
    for (int i = 0; i < 4; ++i) {
        int c = tid + i * 256;
        row[i] = c >> 4;
        cgs[i] = ((c & 15) ^ (row[i] & 7)) * 8;
    }

    f32x4 acc[2][2] = {};
    for (int kt = 0; kt < klen / BK; ++kt) {
        const int k0 = kt * BK;
        #pragma unroll
        for (int i = 0; i < 4; ++i) {
            int c = tid + i * 256;
            gl2lds16(A0 + (size_t)row[i] * klen + k0 + cgs[i], &As[c * 8]);
            gl2lds16(B0 + (size_t)row[i] * klen + k0 + cgs[i], &Bs[c * 8]);
        }
        __syncthreads();
        #pragma unroll
        for (int ks = 0; ks < 4; ++ks) {
            bf16x8 af[2], bfr[2];
            const int g = ks * 4 + lq;
            #pragma unroll
            for (int mt = 0; mt < 2; ++mt) {
                int m = wm + mt * 16 + lr;
                af[mt] = *(const bf16x8*)&As[(m * CHK + (g ^ (m & 7))) * 8];
            }
            #pragma unroll
            for (int nt = 0; nt < 2; ++nt) {
                int n = wn + nt * 16 + lr;
                bfr[nt] = *(const bf16x8*)&Bs[(n * CHK + (g ^ (n & 7))) * 8];
            }
            #pragma unroll
            for (int mt = 0; mt < 2; ++mt) {
                #pragma unroll
                for (int nt = 0; nt < 2; ++nt) {
                    acc[mt][nt] = __builtin_amdgcn_mfma_f32_16x16x32_bf16(af[mt], bfr[nt], acc[mt][nt], 0, 0, 0);
                }
            }
        }
        __syncthreads();
    }
    #pragma unroll
    for (int mt = 0; mt < 2; ++mt) {
        #pragma unroll
        for (int r = 0; r < 4; ++r) {
            int m = wm + mt * 16 + lq * 4 + r;
            int slot = m0 + m;
            if (slot < cnt) {
                int t = routed ? tokidx[e * TTOK + slot] : slot;
                #pragma unroll
                for (int nt = 0; nt < 2; ++nt) {
                    int n = wn + nt * 16 + lr;
                    unsafeAtomicAdd(&out[(size_t)t * DIMSZ + n0 + n], acc[mt][nt][r]);
                }
            }
        }
    }
}

extern "C" void kernel_launch(void* const* d_in, const int* in_sizes, int n_in,
                              void* d_out, int out_size, void* d_ws, size_t ws_size,
                              hipStream_t stream) {
    const float* x      = (const float*)d_in[0];
    const float* gate_w = (const float*)d_in[1];
    const float* w1     = (const float*)d_in[2];
    const float* w2     = (const float*)d_in[3];
    const float* w3     = (const float*)d_in[4];
    const float* sw1    = (const float*)d_in[5];
    const float* sw2    = (const float*)d_in[6];
    const float* sw3    = (const float*)d_in[7];
    float* out = (float*)d_out;

    char* ws = (char*)d_ws;
    const size_t SZ_W   = (size_t)(NROUT + 2) * INTERSZ * DIMSZ * 2;
    const size_t SZ_XBF = (size_t)TTOK * DIMSZ * 2;
    u16*   W1b    = (u16*)(ws);
    u16*   W3b    = (u16*)(ws + SZ_W);
    u16*   W2all  = (u16*)(ws + 2 * SZ_W);
    u16*   Xbf    = (u16*)(ws + 3 * SZ_W);
    char*  route  = ws + 3 * SZ_W + SZ_XBF;
    int*   counts = (int*)route;
    int*   topi   = (int*)(route + 256);
    float2* topw  = (float2*)(route + 256 + TTOK * 4);
    int*   tokidx = (int*)(route + 256 + TTOK * 12);
    float* tokw   = (float*)(route + 256 + TTOK * 12 + 16 * TTOK * 4);
    char*  hbuf   = route + 256 + TTOK * 12 + 2 * (size_t)16 * TTOK * 4;
    u16*   Hc     = (u16*)hbuf;                                        // [16][2048][512]
    u16*   Hs     = (u16*)(hbuf + (size_t)NROUT * TTOK * INTERSZ * 2); // [2048][1024]
    u16*   W2sb   = W2all + (size_t)NROUT * DIMSZ * INTERSZ;

    prep<<<dim3(2048, 4), 256, 0, stream>>>(
        w1, sw1, w3, sw3, w2, sw2, W1b, W3b, W2all,
        x, gate_w, topi, topw, Xbf, out);
    route_kernel<<<NROUT, 256, 0, stream>>>(topi, topw, counts, tokidx, tokw);
    gemm1s<<<dim3(INTERSZ / 64, TTOK / 64, NROUT + 2), 256, 0, stream>>>(
        Xbf, W1b, W3b, counts, tokidx, tokw, Hc, Hs);
    gemm2u<<<dim3(DIMSZ / 64, TTOK / 64, NROUT + 1), 256, 0, stream>>>(
        Hc, Hs, W2all, W2sb, counts, tokidx, out);
}

// Round 4
// 233.452 us; speedup vs baseline: 1.1527x; 1.0035x over previous
//
#include <hip/hip_runtime.h>
#include <stdint.h>

typedef unsigned short u16;
typedef __bf16 bf16x8 __attribute__((ext_vector_type(8)));
typedef float f32x4 __attribute__((ext_vector_type(4)));
typedef unsigned short u16x8 __attribute__((ext_vector_type(8)));

#define TTOK 2048
#define DIMSZ 1024
#define NROUT 16
#define INTERSZ 512
#define BK 128
#define CHK 16   // BK/8 chunks of 8 u16 per row

__device__ __forceinline__ u16 f2bf(float f) {
    unsigned int u = __builtin_bit_cast(unsigned int, f);
    unsigned int r = u + 0x7FFFu + ((u >> 16) & 1u);
    return (u16)(r >> 16);
}

__device__ __forceinline__ void gl2lds16(const void* g, void* l) {
    __builtin_amdgcn_global_load_lds(
        (const __attribute__((address_space(1))) void*)(uintptr_t)g,
        (__attribute__((address_space(3))) void*)(uintptr_t)l,
        16, 0, 0);
}

// ---- prep: grid.y<3 = weight cast groups; grid.y==3 = gate + Xbf + zero(out) ----
// Cast pattern: 1 float4 load -> 1 ushort4 store per slot, lanes CONTIGUOUS in
// both (16B/lane loads, 8B/lane stores). The old 2-float4-per-thread interleave
// had 32B lane stride per instruction -> 2x cache-line request amplification.
#define NF4A (NROUT * INTERSZ * DIMSZ / 4)   // 2,097,152 float4s (routed group)
#define NF4B (DIMSZ * DIMSZ / 4)             // 262,144 float4s (shared group)
#define CASTA_BLKS 1024                      // NF4A / 2048
#define CAST_BLKS 1152                       // + NF4B / 2048
__global__ __launch_bounds__(256) void prep(
    const float* __restrict__ w1, const float* __restrict__ sw1,
    const float* __restrict__ w3, const float* __restrict__ sw3,
    const float* __restrict__ w2, const float* __restrict__ sw2,
    u16* __restrict__ W1b, u16* __restrict__ W3b, u16* __restrict__ W2b,
    const float* __restrict__ x, const float* __restrict__ gw,
    int* __restrict__ topi, float2* __restrict__ topw,
    u16* __restrict__ Xbf, float* __restrict__ out) {
    const int r = blockIdx.y;
    const int tid = threadIdx.x;
    if (r < 3) {
        if (blockIdx.x >= CAST_BLKS) return;
        const float* a; const float* b; u16* d;
        if (r == 0)      { a = w1; b = sw1; d = W1b; }
        else if (r == 1) { a = w3; b = sw3; d = W3b; }
        else             { a = w2; b = sw2; d = W2b; }
        // block-uniform source select (a/b boundary falls on block boundary)
        const float4* src = (blockIdx.x < CASTA_BLKS)
                            ? (const float4*)a
                            : (const float4*)b - (size_t)CASTA_BLKS * 2048;
        ushort4* dst = (ushort4*)d;
        const size_t gbase = (size_t)blockIdx.x * 2048;
        float4 v[8];
        #pragma unroll
        for (int k = 0; k < 8; ++k)
            v[k] = src[gbase + k * 256 + tid];
        #pragma unroll
        for (int k = 0; k < 8; ++k) {
            ushort4 o;
            o.x = f2bf(v[k].x); o.y = f2bf(v[k].y);
            o.z = f2bf(v[k].z); o.w = f2bf(v[k].w);
            dst[gbase + k * 256 + tid] = o;
        }
        return;
    }
    // gate branch: one block per token
    const int t = blockIdx.x;
    const int wave = tid >> 6, lane = tid & 63;
    const int d0 = tid * 4;
    *(float4*)(out + (size_t)t * DIMSZ + d0) = make_float4(0.f, 0.f, 0.f, 0.f);
    float4 xv = *(const float4*)(x + (size_t)t * DIMSZ + d0);
    ushort4 o;
    o.x = f2bf(xv.x); o.y = f2bf(xv.y); o.z = f2bf(xv.z); o.w = f2bf(xv.w);
    *(ushort4*)&Xbf[(size_t)t * DIMSZ + d0] = o;

    float acc[16];
    #pragma unroll
    for (int e = 0; e < 16; ++e) {
        float4 g = *(const float4*)(gw + e * DIMSZ + d0);
        acc[e] = xv.x * g.x + xv.y * g.y + xv.z * g.z + xv.w * g.w;
    }
    #pragma unroll
    for (int off = 32; off > 0; off >>= 1) {
        #pragma unroll
        for (int e = 0; e < 16; ++e) acc[e] += __shfl_xor(acc[e], off);
    }
    __shared__ float part[4][16];
    __shared__ float sfin[16];
    if (lane < 16) part[wave][lane] = acc[lane];
    __syncthreads();
    if (wave == 0 && lane < 16) {
        float s = part[0][lane] + part[1][lane] + part[2][lane] + part[3][lane];
        sfin[lane] = 1.f / (1.f + expf(-s));
    }
    __syncthreads();
    if (tid == 0) {
        int i0 = 0; float v0 = sfin[0];
        #pragma unroll
        for (int e = 1; e < 16; ++e) { float v = sfin[e]; if (v > v0) { v0 = v; i0 = e; } }
        int i1 = -1; float v1 = -1e30f;
        #pragma unroll
        for (int e = 0; e < 16; ++e) { float v = sfin[e]; if (e != i0 && v > v1) { v1 = v; i1 = e; } }
        float inv = 1.f / (v0 + v1);
        topi[t] = i0 | (i1 << 8);
        topw[t] = make_float2(v0 * inv, v1 * inv);
    }
}

// ---- route: one block per expert; block-wide prefix sum -> ordered compact lists ----
__global__ __launch_bounds__(256) void route_kernel(
    const int* __restrict__ topi, const float2* __restrict__ topw,
    int* __restrict__ counts, int* __restrict__ tokidx, float* __restrict__ tokw) {
    const int e = blockIdx.x;
    const int tid = threadIdx.x;
    int p[8]; int m[8]; int cnt = 0;
    #pragma unroll
    for (int j = 0; j < 8; ++j) {
        int t = tid * 8 + j;
        p[j] = topi[t];
        m[j] = ((p[j] & 255) == e) || ((p[j] >> 8) == e) ? 1 : 0;
        cnt += m[j];
    }
    const int lane = tid & 63, wave = tid >> 6;
    int v = cnt;
    #pragma unroll
    for (int off = 1; off < 64; off <<= 1) {
        int u = __shfl_up(v, off);
        if (lane >= off) v += u;
    }
    __shared__ int wsum[4];
    if (lane == 63) wsum[wave] = v;
    __syncthreads();
    int wbase = 0;
    #pragma unroll
    for (int w = 0; w < 4; ++w) wbase += (w < wave) ? wsum[w] : 0;
    int base = wbase + v - cnt;
    #pragma unroll
    for (int j = 0; j < 8; ++j) {
        if (m[j]) {
            int t = tid * 8 + j;
            float2 w2 = topw[t];
            tokidx[e * TTOK + base] = t;
            tokw[e * TTOK + base] = ((p[j] & 255) == e) ? w2.x : w2.y;
            ++base;
        }
    }
    if (tid == 0) counts[e] = wsum[0] + wsum[1] + wsum[2] + wsum[3];
}

// ---- GEMM1 sparse: BM=64 BN=64 BK=128, 4 waves (2x2), wave tile 32x32 ----
// z < NROUT routed, z in {16,17} shared halves. bf16 weights via global_load_lds.
__global__ __launch_bounds__(256) void gemm1s(
    const u16* __restrict__ Xbf, const u16* __restrict__ W1b,
    const u16* __restrict__ W3b, const int* __restrict__ counts,
    const int* __restrict__ tokidx, const float* __restrict__ tokw,
    u16* __restrict__ Hc, u16* __restrict__ Hs) {
    const int e = blockIdx.z;
    const int cnt = (e < NROUT) ? counts[e] : TTOK;
    const int m0 = blockIdx.y * 64;
    if (m0 >= cnt) return;
    const int n0 = blockIdx.x * 64;
    __shared__ u16 As[64 * BK], B1s[64 * BK], B3s[64 * BK];
    // shared halves (e=16,17) are appended rows of W1b/W3b: base row = e*INTERSZ + n0
    const u16* B1 = W1b + ((size_t)e * INTERSZ + n0) * DIMSZ;
    const u16* B3 = W3b + ((size_t)e * INTERSZ + n0) * DIMSZ;
    const int tid = threadIdx.x;

    int row[4], cgs[4]; size_t arow[4];
    #pragma unroll
    for (int i = 0; i < 4; ++i) {
        int c = tid + i * 256;
        row[i] = c >> 4;
        cgs[i] = ((c & 15) ^ (row[i] & 7)) * 8;
        int slot = m0 + row[i];
        int g;
        if (e < NROUT) g = (slot < cnt) ? tokidx[e * TTOK + slot] : 0;
        else           g = slot;
        arow[i] = (size_t)g * DIMSZ;
    }
    f32x4 acc1[2][2] = {}; f32x4 acc3[2][2] = {};
    const int wave = tid >> 6, lane = tid & 63;
    const int wm = (wave >> 1) * 32, wn = (wave & 1) * 32;
    const int lr = lane & 15, lq = lane >> 4;

    for (int kt = 0; kt < DIMSZ / BK; ++kt) {
        const int k0 = kt * BK;
        #pragma unroll
        for (int i = 0; i < 4; ++i) {
            int c = tid + i * 256;
            gl2lds16(Xbf + arow[i] + k0 + cgs[i], &As[c * 8]);
            size_t boff = (size_t)row[i] * DIMSZ + k0 + cgs[i];
            gl2lds16(B1 + boff, &B1s[c * 8]);
            gl2lds16(B3 + boff, &B3s[c * 8]);
        }
        __syncthreads();
        #pragma unroll
        for (int ks = 0; ks < 4; ++ks) {
            bf16x8 af[2], b1f[2], b3f[2];
            const int g = ks * 4 + lq;
            #pragma unroll
            for (int mt = 0; mt < 2; ++mt) {
                int m = wm + mt * 16 + lr;
                af[mt] = *(const bf16x8*)&As[(m * CHK + (g ^ (m & 7))) * 8];
            }
            #pragma unroll
            for (int nt = 0; nt < 2; ++nt) {
                int n = wn + nt * 16 + lr;
                int ch = (n * CHK + (g ^ (n & 7))) * 8;
                b1f[nt] = *(const bf16x8*)&B1s[ch];
                b3f[nt] = *(const bf16x8*)&B3s[ch];
            }
            #pragma unroll
            for (int mt = 0; mt < 2; ++mt) {
                #pragma unroll
                for (int nt = 0; nt < 2; ++nt) {
                    acc1[mt][nt] = __builtin_amdgcn_mfma_f32_16x16x32_bf16(af[mt], b1f[nt], acc1[mt][nt], 0, 0, 0);
                    acc3[mt][nt] = __builtin_amdgcn_mfma_f32_16x16x32_bf16(af[mt], b3f[nt], acc3[mt][nt], 0, 0, 0);
                }
            }
        }
        __syncthreads();
    }
    #pragma unroll
    for (int mt = 0; mt < 2; ++mt) {
        #pragma unroll
        for (int nt = 0; nt < 2; ++nt) {
            #pragma unroll
            for (int r = 0; r < 4; ++r) {
                int m = wm + mt * 16 + lq * 4 + r;
                int n = wn + nt * 16 + lr;
                int slot = m0 + m;
                bool valid = slot < cnt;
                float h1 = acc1[mt][nt][r], h3 = acc3[mt][nt][r];
                float hv = 0.f;
                if (valid) {
                    float tw = (e < NROUT) ? tokw[e * TTOK + slot] : 1.0f;
                    hv = h1 / (1.f + __expf(-h1)) * h3 * tw;
                }
                if (e < NROUT)
                    Hc[((size_t)e * TTOK + slot) * INTERSZ + n0 + n] = f2bf(hv);
                else
                    Hs[(size_t)slot * DIMSZ + (e - NROUT) * INTERSZ + n0 + n] = f2bf(hv);
            }
        }
    }
}

// ---- GEMM2 unified: BM=64 BN=64 BK=128; out zero-initialized, atomicAdd ----
// z<16 routed (K=512), z==16 shared (K=1024, identity rows)
__global__ __launch_bounds__(256) void gemm2u(
    const u16* __restrict__ Hc, const u16* __restrict__ Hs,
    const u16* __restrict__ W2b, const u16* __restrict__ W2sb,
    const int* __restrict__ counts, const int* __restrict__ tokidx,
    float* __restrict__ out) {
    const int e = blockIdx.z;
    const bool routed = (e < NROUT);
    const int cnt = routed ? counts[e] : TTOK;
    const int m0 = blockIdx.y * 64;
    if (m0 >= cnt) return;
    const int n0 = blockIdx.x * 64;
    const int klen = routed ? INTERSZ : DIMSZ;
    __shared__ u16 As[64 * BK], Bs[64 * BK];
    const u16* A0 = routed ? Hc + ((size_t)e * TTOK + m0) * INTERSZ
                           : Hs + (size_t)m0 * DIMSZ;
    const u16* B0 = routed ? W2b + ((size_t)e * DIMSZ + n0) * INTERSZ
                           : W2sb + (size_t)n0 * DIMSZ;
    const int tid = threadIdx.x;
    const int wave = tid >> 6, lane = tid & 63;
    const int wm = (wave >> 1) * 32, wn = (wave & 1) * 32;
    const int lr = lane & 15, lq = lane >> 4;

    int row[4], cgs[4];
    #pragma unroll
    for (int i = 0; i < 4; ++i) {
        int c = tid + i * 256;
        row[i] = c >> 4;
        cgs[i] = ((c & 15) ^ (row[i] & 7)) * 8;
    }

    f32x4 acc[2][2] = {};
    for (int kt = 0; kt < klen / BK; ++kt) {
        const int k0 = kt * BK;
        #pragma unroll
        for (int i = 0; i < 4; ++i) {
            int c = tid + i * 256;
            gl2lds16(A0 + (size_t)row[i] * klen + k0 + cgs[i], &As[c * 8]);
            gl2lds16(B0 + (size_t)row[i] * klen + k0 + cgs[i], &Bs[c * 8]);
        }
        __syncthreads();
        #pragma unroll
        for (int ks = 0; ks < 4; ++ks) {
            bf16x8 af[2], bfr[2];
            const int g = ks * 4 + lq;
            #pragma unroll
            for (int mt = 0; mt < 2; ++mt) {
                int m = wm + mt * 16 + lr;
                af[mt] = *(const bf16x8*)&As[(m * CHK + (g ^ (m & 7))) * 8];
            }
            #pragma unroll
            for (int nt = 0; nt < 2; ++nt) {
                int n = wn + nt * 16 + lr;
                bfr[nt] = *(const bf16x8*)&Bs[(n * CHK + (g ^ (n & 7))) * 8];
            }
            #pragma unroll
            for (int mt = 0; mt < 2; ++mt) {
                #pragma unroll
                for (int nt = 0; nt < 2; ++nt) {
                    acc[mt][nt] = __builtin_amdgcn_mfma_f32_16x16x32_bf16(af[mt], bfr[nt], acc[mt][nt], 0, 0, 0);
                }
            }
        }
        __syncthreads();
    }
    #pragma unroll
    for (int mt = 0; mt < 2; ++mt) {
        #pragma unroll
        for (int r = 0; r < 4; ++r) {
            int m = wm + mt * 16 + lq * 4 + r;
            int slot = m0 + m;
            if (slot < cnt) {
                int t = routed ? tokidx[e * TTOK + slot] : slot;
                #pragma unroll
                for (int nt = 0; nt < 2; ++nt) {
                    int n = wn + nt * 16 + lr;
                    unsafeAtomicAdd(&out[(size_t)t * DIMSZ + n0 + n], acc[mt][nt][r]);
                }
            }
        }
    }
}

extern "C" void kernel_launch(void* const* d_in, const int* in_sizes, int n_in,
                              void* d_out, int out_size, void* d_ws, size_t ws_size,
                              hipStream_t stream) {
    const float* x      = (const float*)d_in[0];
    const float* gate_w = (const float*)d_in[1];
    const float* w1     = (const float*)d_in[2];
    const float* w2     = (const float*)d_in[3];
    const float* w3     = (const float*)d_in[4];
    const float* sw1    = (const float*)d_in[5];
    const float* sw2    = (const float*)d_in[6];
    const float* sw3    = (const float*)d_in[7];
    float* out = (float*)d_out;

    char* ws = (char*)d_ws;
    const size_t SZ_W   = (size_t)(NROUT + 2) * INTERSZ * DIMSZ * 2;
    const size_t SZ_XBF = (size_t)TTOK * DIMSZ * 2;
    u16*   W1b    = (u16*)(ws);
    u16*   W3b    = (u16*)(ws + SZ_W);
    u16*   W2all  = (u16*)(ws + 2 * SZ_W);
    u16*   Xbf    = (u16*)(ws + 3 * SZ_W);
    char*  route  = ws + 3 * SZ_W + SZ_XBF;
    int*   counts = (int*)route;
    int*   topi   = (int*)(route + 256);
    float2* topw  = (float2*)(route + 256 + TTOK * 4);
    int*   tokidx = (int*)(route + 256 + TTOK * 12);
    float* tokw   = (float*)(route + 256 + TTOK * 12 + 16 * TTOK * 4);
    char*  hbuf   = route + 256 + TTOK * 12 + 2 * (size_t)16 * TTOK * 4;
    u16*   Hc     = (u16*)hbuf;                                        // [16][2048][512]
    u16*   Hs     = (u16*)(hbuf + (size_t)NROUT * TTOK * INTERSZ * 2); // [2048][1024]
    u16*   W2sb   = W2all + (size_t)NROUT * DIMSZ * INTERSZ;

    prep<<<dim3(2048, 4), 256, 0, stream>>>(
        w1, sw1, w3, sw3, w2, sw2, W1b, W3b, W2all,
        x, gate_w, topi, topw, Xbf, out);
    route_kernel<<<NROUT, 256, 0, stream>>>(topi, topw, counts, tokidx, tokw);
    gemm1s<<<dim3(INTERSZ / 64, TTOK / 64, NROUT + 2), 256, 0, stream>>>(
        Xbf, W1b, W3b, counts, tokidx, tokw, Hc, Hs);
    gemm2u<<<dim3(DIMSZ / 64, TTOK / 64, NROUT + 1), 256, 0, stream>>>(
        Hc, Hs, W2all, W2sb, counts, tokidx, out);
}

// Round 5
// 230.798 us; speedup vs baseline: 1.1659x; 1.0115x over previous
//
#include <hip/hip_runtime.h>
#include <stdint.h>

typedef unsigned short u16;
typedef __bf16 bf16x8 __attribute__((ext_vector_type(8)));
typedef float f32x4 __attribute__((ext_vector_type(4)));
typedef unsigned short u16x8 __attribute__((ext_vector_type(8)));

#define TTOK 2048
#define DIMSZ 1024
#define NROUT 16
#define INTERSZ 512
#define BK 128
#define CHK 16   // BK/8 chunks of 8 u16 per row

__device__ __forceinline__ u16 f2bf(float f) {
    unsigned int u = __builtin_bit_cast(unsigned int, f);
    unsigned int r = u + 0x7FFFu + ((u >> 16) & 1u);
    return (u16)(r >> 16);
}

__device__ __forceinline__ void gl2lds16(const void* g, void* l) {
    __builtin_amdgcn_global_load_lds(
        (const __attribute__((address_space(1))) void*)(uintptr_t)g,
        (__attribute__((address_space(3))) void*)(uintptr_t)l,
        16, 0, 0);
}

// ---- prep: grid.y<3 = weight cast groups; grid.y==3 = gate + Xbf ----
// (out zero-init removed: gemm2sh plain-stores every element exactly once)
#define NF4A (NROUT * INTERSZ * DIMSZ / 4)   // 2,097,152 float4s (routed group)
#define NF4B (DIMSZ * DIMSZ / 4)             // 262,144 float4s (shared group)
#define CASTA_BLKS 1024                      // NF4A / 2048
#define CAST_BLKS 1152                       // + NF4B / 2048
__global__ __launch_bounds__(256) void prep(
    const float* __restrict__ w1, const float* __restrict__ sw1,
    const float* __restrict__ w3, const float* __restrict__ sw3,
    const float* __restrict__ w2, const float* __restrict__ sw2,
    u16* __restrict__ W1b, u16* __restrict__ W3b, u16* __restrict__ W2b,
    const float* __restrict__ x, const float* __restrict__ gw,
    int* __restrict__ topi, float2* __restrict__ topw,
    u16* __restrict__ Xbf) {
    const int r = blockIdx.y;
    const int tid = threadIdx.x;
    if (r < 3) {
        if (blockIdx.x >= CAST_BLKS) return;
        const float* a; const float* b; u16* d;
        if (r == 0)      { a = w1; b = sw1; d = W1b; }
        else if (r == 1) { a = w3; b = sw3; d = W3b; }
        else             { a = w2; b = sw2; d = W2b; }
        // block-uniform source select (a/b boundary falls on block boundary)
        const float4* src = (blockIdx.x < CASTA_BLKS)
                            ? (const float4*)a
                            : (const float4*)b - (size_t)CASTA_BLKS * 2048;
        ushort4* dst = (ushort4*)d;
        const size_t gbase = (size_t)blockIdx.x * 2048;
        float4 v[8];
        #pragma unroll
        for (int k = 0; k < 8; ++k)
            v[k] = src[gbase + k * 256 + tid];
        #pragma unroll
        for (int k = 0; k < 8; ++k) {
            ushort4 o;
            o.x = f2bf(v[k].x); o.y = f2bf(v[k].y);
            o.z = f2bf(v[k].z); o.w = f2bf(v[k].w);
            dst[gbase + k * 256 + tid] = o;
        }
        return;
    }
    // gate branch: one block per token
    const int t = blockIdx.x;
    const int wave = tid >> 6, lane = tid & 63;
    const int d0 = tid * 4;
    float4 xv = *(const float4*)(x + (size_t)t * DIMSZ + d0);
    ushort4 o;
    o.x = f2bf(xv.x); o.y = f2bf(xv.y); o.z = f2bf(xv.z); o.w = f2bf(xv.w);
    *(ushort4*)&Xbf[(size_t)t * DIMSZ + d0] = o;

    float acc[16];
    #pragma unroll
    for (int e = 0; e < 16; ++e) {
        float4 g = *(const float4*)(gw + e * DIMSZ + d0);
        acc[e] = xv.x * g.x + xv.y * g.y + xv.z * g.z + xv.w * g.w;
    }
    #pragma unroll
    for (int off = 32; off > 0; off >>= 1) {
        #pragma unroll
        for (int e = 0; e < 16; ++e) acc[e] += __shfl_xor(acc[e], off);
    }
    __shared__ float part[4][16];
    __shared__ float sfin[16];
    if (lane < 16) part[wave][lane] = acc[lane];
    __syncthreads();
    if (wave == 0 && lane < 16) {
        float s = part[0][lane] + part[1][lane] + part[2][lane] + part[3][lane];
        sfin[lane] = 1.f / (1.f + expf(-s));
    }
    __syncthreads();
    if (tid == 0) {
        int i0 = 0; float v0 = sfin[0];
        #pragma unroll
        for (int e = 1; e < 16; ++e) { float v = sfin[e]; if (v > v0) { v0 = v; i0 = e; } }
        int i1 = -1; float v1 = -1e30f;
        #pragma unroll
        for (int e = 0; e < 16; ++e) { float v = sfin[e]; if (e != i0 && v > v1) { v1 = v; i1 = e; } }
        float inv = 1.f / (v0 + v1);
        topi[t] = i0 | (i1 << 8);
        topw[t] = make_float2(v0 * inv, v1 * inv);
    }
}

// ---- route: one block per expert; block-wide prefix sum -> ordered compact lists ----
__global__ __launch_bounds__(256) void route_kernel(
    const int* __restrict__ topi, const float2* __restrict__ topw,
    int* __restrict__ counts, int* __restrict__ tokidx, float* __restrict__ tokw) {
    const int e = blockIdx.x;
    const int tid = threadIdx.x;
    int p[8]; int m[8]; int cnt = 0;
    #pragma unroll
    for (int j = 0; j < 8; ++j) {
        int t = tid * 8 + j;
        p[j] = topi[t];
        m[j] = ((p[j] & 255) == e) || ((p[j] >> 8) == e) ? 1 : 0;
        cnt += m[j];
    }
    const int lane = tid & 63, wave = tid >> 6;
    int v = cnt;
    #pragma unroll
    for (int off = 1; off < 64; off <<= 1) {
        int u = __shfl_up(v, off);
        if (lane >= off) v += u;
    }
    __shared__ int wsum[4];
    if (lane == 63) wsum[wave] = v;
    __syncthreads();
    int wbase = 0;
    #pragma unroll
    for (int w = 0; w < 4; ++w) wbase += (w < wave) ? wsum[w] : 0;
    int base = wbase + v - cnt;
    #pragma unroll
    for (int j = 0; j < 8; ++j) {
        if (m[j]) {
            int t = tid * 8 + j;
            float2 w2 = topw[t];
            tokidx[e * TTOK + base] = t;
            tokw[e * TTOK + base] = ((p[j] & 255) == e) ? w2.x : w2.y;
            ++base;
        }
    }
    if (tid == 0) counts[e] = wsum[0] + wsum[1] + wsum[2] + wsum[3];
}

// ---- GEMM1 sparse: BM=64 BN=64 BK=128, 4 waves (2x2), wave tile 32x32 ----
// z < NROUT routed, z in {16,17} shared halves. bf16 weights via global_load_lds.
__global__ __launch_bounds__(256) void gemm1s(
    const u16* __restrict__ Xbf, const u16* __restrict__ W1b,
    const u16* __restrict__ W3b, const int* __restrict__ counts,
    const int* __restrict__ tokidx, const float* __restrict__ tokw,
    u16* __restrict__ Hc, u16* __restrict__ Hs) {
    const int e = blockIdx.z;
    const int cnt = (e < NROUT) ? counts[e] : TTOK;
    const int m0 = blockIdx.y * 64;
    if (m0 >= cnt) return;
    const int n0 = blockIdx.x * 64;
    __shared__ u16 As[64 * BK], B1s[64 * BK], B3s[64 * BK];
    // shared halves (e=16,17) are appended rows of W1b/W3b: base row = e*INTERSZ + n0
    const u16* B1 = W1b + ((size_t)e * INTERSZ + n0) * DIMSZ;
    const u16* B3 = W3b + ((size_t)e * INTERSZ + n0) * DIMSZ;
    const int tid = threadIdx.x;

    int row[4], cgs[4]; size_t arow[4];
    #pragma unroll
    for (int i = 0; i < 4; ++i) {
        int c = tid + i * 256;
        row[i] = c >> 4;
        cgs[i] = ((c & 15) ^ (row[i] & 7)) * 8;
        int slot = m0 + row[i];
        int g;
        if (e < NROUT) g = (slot < cnt) ? tokidx[e * TTOK + slot] : 0;
        else           g = slot;
        arow[i] = (size_t)g * DIMSZ;
    }
    f32x4 acc1[2][2] = {}; f32x4 acc3[2][2] = {};
    const int wave = tid >> 6, lane = tid & 63;
    const int wm = (wave >> 1) * 32, wn = (wave & 1) * 32;
    const int lr = lane & 15, lq = lane >> 4;

    for (int kt = 0; kt < DIMSZ / BK; ++kt) {
        const int k0 = kt * BK;
        #pragma unroll
        for (int i = 0; i < 4; ++i) {
            int c = tid + i * 256;
            gl2lds16(Xbf + arow[i] + k0 + cgs[i], &As[c * 8]);
            size_t boff = (size_t)row[i] * DIMSZ + k0 + cgs[i];
            gl2lds16(B1 + boff, &B1s[c * 8]);
            gl2lds16(B3 + boff, &B3s[c * 8]);
        }
        __syncthreads();
        #pragma unroll
        for (int ks = 0; ks < 4; ++ks) {
            bf16x8 af[2], b1f[2], b3f[2];
            const int g = ks * 4 + lq;
            #pragma unroll
            for (int mt = 0; mt < 2; ++mt) {
                int m = wm + mt * 16 + lr;
                af[mt] = *(const bf16x8*)&As[(m * CHK + (g ^ (m & 7))) * 8];
            }
            #pragma unroll
            for (int nt = 0; nt < 2; ++nt) {
                int n = wn + nt * 16 + lr;
                int ch = (n * CHK + (g ^ (n & 7))) * 8;
                b1f[nt] = *(const bf16x8*)&B1s[ch];
                b3f[nt] = *(const bf16x8*)&B3s[ch];
            }
            #pragma unroll
            for (int mt = 0; mt < 2; ++mt) {
                #pragma unroll
                for (int nt = 0; nt < 2; ++nt) {
                    acc1[mt][nt] = __builtin_amdgcn_mfma_f32_16x16x32_bf16(af[mt], b1f[nt], acc1[mt][nt], 0, 0, 0);
                    acc3[mt][nt] = __builtin_amdgcn_mfma_f32_16x16x32_bf16(af[mt], b3f[nt], acc3[mt][nt], 0, 0, 0);
                }
            }
        }
        __syncthreads();
    }
    #pragma unroll
    for (int mt = 0; mt < 2; ++mt) {
        #pragma unroll
        for (int nt = 0; nt < 2; ++nt) {
            #pragma unroll
            for (int r = 0; r < 4; ++r) {
                int m = wm + mt * 16 + lq * 4 + r;
                int n = wn + nt * 16 + lr;
                int slot = m0 + m;
                bool valid = slot < cnt;
                float h1 = acc1[mt][nt][r], h3 = acc3[mt][nt][r];
                float hv = 0.f;
                if (valid) {
                    float tw = (e < NROUT) ? tokw[e * TTOK + slot] : 1.0f;
                    hv = h1 / (1.f + __expf(-h1)) * h3 * tw;
                }
                if (e < NROUT)
                    Hc[((size_t)e * TTOK + slot) * INTERSZ + n0 + n] = f2bf(hv);
                else
                    Hs[(size_t)slot * DIMSZ + (e - NROUT) * INTERSZ + n0 + n] = f2bf(hv);
            }
        }
    }
}

// ---- GEMM2 routed: BM=64 BN=64 BK=128, K=512. NO atomics: each token's
// top-1 expert block plain-stores its row into bufA, top-2 into bufB.
__global__ __launch_bounds__(256) void gemm2rt(
    const u16* __restrict__ Hc, const u16* __restrict__ W2b,
    const int* __restrict__ counts, const int* __restrict__ tokidx,
    const int* __restrict__ topi,
    float* __restrict__ bufA, float* __restrict__ bufB) {
    const int e = blockIdx.z;
    const int cnt = counts[e];
    const int m0 = blockIdx.y * 64;
    if (m0 >= cnt) return;
    const int n0 = blockIdx.x * 64;
    __shared__ u16 As[64 * BK], Bs[64 * BK];
    const u16* A0 = Hc + ((size_t)e * TTOK + m0) * INTERSZ;
    const u16* B0 = W2b + ((size_t)e * DIMSZ + n0) * INTERSZ;
    const int tid = threadIdx.x;
    const int wave = tid >> 6, lane = tid & 63;
    const int wm = (wave >> 1) * 32, wn = (wave & 1) * 32;
    const int lr = lane & 15, lq = lane >> 4;

    int row[4], cgs[4];
    #pragma unroll
    for (int i = 0; i < 4; ++i) {
        int c = tid + i * 256;
        row[i] = c >> 4;
        cgs[i] = ((c & 15) ^ (row[i] & 7)) * 8;
    }

    f32x4 acc[2][2] = {};
    for (int kt = 0; kt < INTERSZ / BK; ++kt) {
        const int k0 = kt * BK;
        #pragma unroll
        for (int i = 0; i < 4; ++i) {
            int c = tid + i * 256;
            gl2lds16(A0 + (size_t)row[i] * INTERSZ + k0 + cgs[i], &As[c * 8]);
            gl2lds16(B0 + (size_t)row[i] * INTERSZ + k0 + cgs[i], &Bs[c * 8]);
        }
        __syncthreads();
        #pragma unroll
        for (int ks = 0; ks < 4; ++ks) {
            bf16x8 af[2], bfr[2];
            const int g = ks * 4 + lq;
            #pragma unroll
            for (int mt = 0; mt < 2; ++mt) {
                int m = wm + mt * 16 + lr;
                af[mt] = *(const bf16x8*)&As[(m * CHK + (g ^ (m & 7))) * 8];
            }
            #pragma unroll
            for (int nt = 0; nt < 2; ++nt) {
                int n = wn + nt * 16 + lr;
                bfr[nt] = *(const bf16x8*)&Bs[(n * CHK + (g ^ (n & 7))) * 8];
            }
            #pragma unroll
            for (int mt = 0; mt < 2; ++mt) {
                #pragma unroll
                for (int nt = 0; nt < 2; ++nt) {
                    acc[mt][nt] = __builtin_amdgcn_mfma_f32_16x16x32_bf16(af[mt], bfr[nt], acc[mt][nt], 0, 0, 0);
                }
            }
        }
        __syncthreads();
    }
    #pragma unroll
    for (int mt = 0; mt < 2; ++mt) {
        #pragma unroll
        for (int r = 0; r < 4; ++r) {
            int m = wm + mt * 16 + lq * 4 + r;
            int slot = m0 + m;
            if (slot < cnt) {
                int t = tokidx[e * TTOK + slot];
                float* db = ((topi[t] & 255) == e) ? bufA : bufB;
                #pragma unroll
                for (int nt = 0; nt < 2; ++nt) {
                    int n = wn + nt * 16 + lr;
                    db[(size_t)t * DIMSZ + n0 + n] = acc[mt][nt][r];
                }
            }
        }
    }
}

// ---- GEMM2 shared: BM=64 BN=64 BK=128, K=1024, identity rows; epilogue
// combines shared acc + bufA + bufB and writes out ONCE (no zero-init needed).
__global__ __launch_bounds__(256) void gemm2sh(
    const u16* __restrict__ Hs, const u16* __restrict__ W2sb,
    const float* __restrict__ bufA, const float* __restrict__ bufB,
    float* __restrict__ out) {
    const int m0 = blockIdx.y * 64;
    const int n0 = blockIdx.x * 64;
    __shared__ u16 As[64 * BK], Bs[64 * BK];
    const u16* A0 = Hs + (size_t)m0 * DIMSZ;
    const u16* B0 = W2sb + (size_t)n0 * DIMSZ;
    const int tid = threadIdx.x;
    const int wave = tid >> 6, lane = tid & 63;
    const int wm = (wave >> 1) * 32, wn = (wave & 1) * 32;
    const int lr = lane & 15, lq = lane >> 4;

    int row[4], cgs[4];
    #pragma unroll
    for (int i = 0; i < 4; ++i) {
        int c = tid + i * 256;
        row[i] = c >> 4;
        cgs[i] = ((c & 15) ^ (row[i] & 7)) * 8;
    }

    f32x4 acc[2][2] = {};
    for (int kt = 0; kt < DIMSZ / BK; ++kt) {
        const int k0 = kt * BK;
        #pragma unroll
        for (int i = 0; i < 4; ++i) {
            int c = tid + i * 256;
            gl2lds16(A0 + (size_t)row[i] * DIMSZ + k0 + cgs[i], &As[c * 8]);
            gl2lds16(B0 + (size_t)row[i] * DIMSZ + k0 + cgs[i], &Bs[c * 8]);
        }
        __syncthreads();
        #pragma unroll
        for (int ks = 0; ks < 4; ++ks) {
            bf16x8 af[2], bfr[2];
            const int g = ks * 4 + lq;
            #pragma unroll
            for (int mt = 0; mt < 2; ++mt) {
                int m = wm + mt * 16 + lr;
                af[mt] = *(const bf16x8*)&As[(m * CHK + (g ^ (m & 7))) * 8];
            }
            #pragma unroll
            for (int nt = 0; nt < 2; ++nt) {
                int n = wn + nt * 16 + lr;
                bfr[nt] = *(const bf16x8*)&Bs[(n * CHK + (g ^ (n & 7))) * 8];
            }
            #pragma unroll
            for (int mt = 0; mt < 2; ++mt) {
                #pragma unroll
                for (int nt = 0; nt < 2; ++nt) {
                    acc[mt][nt] = __builtin_amdgcn_mfma_f32_16x16x32_bf16(af[mt], bfr[nt], acc[mt][nt], 0, 0, 0);
                }
            }
        }
        __syncthreads();
    }
    #pragma unroll
    for (int mt = 0; mt < 2; ++mt) {
        #pragma unroll
        for (int r = 0; r < 4; ++r) {
            int t = m0 + wm + mt * 16 + lq * 4 + r;
            #pragma unroll
            for (int nt = 0; nt < 2; ++nt) {
                int n = wn + nt * 16 + lr;
                size_t idx = (size_t)t * DIMSZ + n0 + n;
                out[idx] = acc[mt][nt][r] + bufA[idx] + bufB[idx];
            }
        }
    }
}

extern "C" void kernel_launch(void* const* d_in, const int* in_sizes, int n_in,
                              void* d_out, int out_size, void* d_ws, size_t ws_size,
                              hipStream_t stream) {
    const float* x      = (const float*)d_in[0];
    const float* gate_w = (const float*)d_in[1];
    const float* w1     = (const float*)d_in[2];
    const float* w2     = (const float*)d_in[3];
    const float* w3     = (const float*)d_in[4];
    const float* sw1    = (const float*)d_in[5];
    const float* sw2    = (const float*)d_in[6];
    const float* sw3    = (const float*)d_in[7];
    float* out = (float*)d_out;

    char* ws = (char*)d_ws;
    const size_t SZ_W   = (size_t)(NROUT + 2) * INTERSZ * DIMSZ * 2;
    const size_t SZ_XBF = (size_t)TTOK * DIMSZ * 2;
    u16*   W1b    = (u16*)(ws);
    u16*   W3b    = (u16*)(ws + SZ_W);
    u16*   W2all  = (u16*)(ws + 2 * SZ_W);
    u16*   Xbf    = (u16*)(ws + 3 * SZ_W);
    char*  route  = ws + 3 * SZ_W + SZ_XBF;
    int*   counts = (int*)route;
    int*   topi   = (int*)(route + 256);
    float2* topw  = (float2*)(route + 256 + TTOK * 4);
    int*   tokidx = (int*)(route + 256 + TTOK * 12);
    float* tokw   = (float*)(route + 256 + TTOK * 12 + 16 * TTOK * 4);
    char*  hbuf   = route + 256 + TTOK * 12 + 2 * (size_t)16 * TTOK * 4;
    u16*   Hc     = (u16*)hbuf;                                        // [16][2048][512]
    u16*   Hs     = (u16*)(hbuf + (size_t)NROUT * TTOK * INTERSZ * 2); // [2048][1024]
    char*  bufs   = hbuf + (size_t)NROUT * TTOK * INTERSZ * 2 + (size_t)TTOK * DIMSZ * 2;
    float* bufA   = (float*)bufs;                                      // [2048][1024] fp32
    float* bufB   = (float*)(bufs + (size_t)TTOK * DIMSZ * 4);
    u16*   W2sb   = W2all + (size_t)NROUT * DIMSZ * INTERSZ;

    prep<<<dim3(2048, 4), 256, 0, stream>>>(
        w1, sw1, w3, sw3, w2, sw2, W1b, W3b, W2all,
        x, gate_w, topi, topw, Xbf);
    route_kernel<<<NROUT, 256, 0, stream>>>(topi, topw, counts, tokidx, tokw);
    gemm1s<<<dim3(INTERSZ / 64, TTOK / 64, NROUT + 2), 256, 0, stream>>>(
        Xbf, W1b, W3b, counts, tokidx, tokw, Hc, Hs);
    gemm2rt<<<dim3(DIMSZ / 64, TTOK / 64, NROUT), 256, 0, stream>>>(
        Hc, W2all, counts, tokidx, topi, bufA, bufB);
    gemm2sh<<<dim3(DIMSZ / 64, TTOK / 64), 256, 0, stream>>>(
        Hs, W2sb, bufA, bufB, out);
}